// Round 6
// baseline (2013.138 us; speedup 1.0000x reference)
//
#include <hip/hip_runtime.h>

#define NROWS 32768
#define DDIM  512
#define KCENT 8192
#define BM 64               // rows per block

// out layout (floats): qout[16777216] loss[16777216] idx[32768] cbv[4194304] counts[8192]
#define O_LOSS 16777216
#define O_IDX  33554432
#define O_CBV  33587200
#define O_CNT  37781504

#define XT_BYTES 65536      // 64 rows * 1024 B (512 f16)

typedef float f32x4 __attribute__((ext_vector_type(4)));
typedef _Float16 f16x8 __attribute__((ext_vector_type(8)));

// ---- kernel 0a: fp32 -> f16, plain row-major (for X) ----
__global__ __launch_bounds__(256) void vq_cvt_plain(
    const float* __restrict__ src, char* __restrict__ dst)
{
    const size_t gid = (size_t)blockIdx.x * 256 + threadIdx.x;  // one 16B unit
    const float4* p = (const float4*)(src + gid * 8);
    float4 a = p[0], b = p[1];
    f16x8 h;
    h[0]=(_Float16)a.x; h[1]=(_Float16)a.y; h[2]=(_Float16)a.z; h[3]=(_Float16)a.w;
    h[4]=(_Float16)b.x; h[5]=(_Float16)b.y; h[6]=(_Float16)b.z; h[7]=(_Float16)b.w;
    *(f16x8*)(dst + gid * 16) = h;
}

// ---- kernel 0b: CB fp32 -> f16 chunked: [S 0..1023][r 0..127][w 0..3] 16B units
// chunk S = tile(S>>4) x kstep(S&15); unit (S,r,w) = row (S>>4)*128+r, dims (S&15)*32 + w*8
__global__ __launch_bounds__(256) void vq_cvt_cb(
    const float* __restrict__ src, char* __restrict__ dst)
{
    const int gid = blockIdx.x * 256 + threadIdx.x;
    const int S = gid >> 9, r = (gid >> 2) & 127, w = gid & 3;
    const float4* p = (const float4*)(src + (size_t)((S >> 4)*128 + r) * DDIM
                                      + (S & 15)*32 + w*8);
    float4 a = p[0], b = p[1];
    f16x8 h;
    h[0]=(_Float16)a.x; h[1]=(_Float16)a.y; h[2]=(_Float16)a.z; h[3]=(_Float16)a.w;
    h[4]=(_Float16)b.x; h[5]=(_Float16)b.y; h[6]=(_Float16)b.z; h[7]=(_Float16)b.w;
    *(f16x8*)(dst + (size_t)gid * 16) = h;
}

// ---- kernel 1: centroid squared norms (fp64 accumulate) + counts=1 ----
__global__ __launch_bounds__(256) void vq_cnorm_kernel(
    const float* __restrict__ CB, float* __restrict__ cnorm, float* __restrict__ counts)
{
    const int wid  = threadIdx.x >> 6;
    const int lane = threadIdx.x & 63;
    const int cid  = blockIdx.x * 4 + wid;
    const float4* p = (const float4*)(CB + (size_t)cid * DDIM + lane * 8);
    float4 a = p[0], b = p[1];
    double s = (double)a.x*a.x + (double)a.y*a.y + (double)a.z*a.z + (double)a.w*a.w
             + (double)b.x*b.x + (double)b.y*b.y + (double)b.z*b.z + (double)b.w*b.w;
    #pragma unroll
    for (int off = 32; off > 0; off >>= 1) s += __shfl_down(s, off);
    if (lane == 0) { cnorm[cid] = (float)s; counts[cid] = 1.0f; }
}

__device__ __forceinline__ void t2_update(float s, int c,
                                          float& v1, int& i1, float& v2, int& i2)
{
    if (s < v1)      { v2 = v1; i2 = i1; v1 = s; i1 = c; }
    else if (s < v2) { v2 = s;  i2 = c; }
}

__device__ __forceinline__ void t2_merge(float b1, int bi1, float b2, int bi2,
                                         float& a1, int& ai1, float& a2, int& ai2)
{
    if (b1 < a1 || (b1 == a1 && bi1 < ai1)) {
        float o1 = a1; int oi1 = ai1;
        a1 = b1; ai1 = bi1;
        if (b2 < o1 || (b2 == o1 && bi2 < oi1)) { a2 = b2; ai2 = bi2; }
        else                                    { a2 = o1; ai2 = oi1; }
    } else {
        if (b1 < a2 || (b1 == a2 && bi1 < ai2)) { a2 = b1; ai2 = bi1; }
    }
}

// ---- kernel 2: barrier-free f16 distance GEMM + per-split top-2 ----
// 256 thr, 4 waves each 64 rows x 32 cols (m=4,n=2); X LDS-resident;
// B global->reg pipeline depth 3 (4 static buffers); no barriers in main loop.
__global__ __launch_bounds__(256, 2) void vq_topk_kernel(
    const char* __restrict__ Xf, const char* __restrict__ Cf,
    const float* __restrict__ cnorm, int* __restrict__ pmini4)
{
    __shared__ __align__(16) char lds[XT_BYTES];   // 64 KB

    const int bid   = blockIdx.x;
    const int split = (bid >> 2) & 1;                     // XCD 0-3: split0, 4-7: split1
    const int rbi   = (bid & 3) * 128 + (bid >> 3);       // 0..511 per split (bijective)
    const int rb    = rbi * BM;
    const int t     = threadIdx.x;
    const int lane  = t & 63;
    const int wid   = t >> 6;        // = wc, 4 col-groups of 32
    const int l15   = lane & 15;
    const int lg    = lane >> 4;
    const int axor  = l15 & 7;

    // ---- stage X tile (64 KB), 8-slot XOR swizzle ----
    #pragma unroll
    for (int i = 0; i < 16; ++i) {
        const int g = i*256 + t, r = g >> 6, w = g & 63;
        uint4 d = *(const uint4*)(Xf + (size_t)rb*1024 + (size_t)g*16);
        *(uint4*)(&lds[r*1024 + ((w ^ (r & 7)) * 16)]) = d;
    }

    // per-lane B base: chunk S stride 8192 B; within chunk: row*64 + kslot*16
    const char* bbase = Cf + (size_t)split*512*8192 + (size_t)((wid*32 + l15)*64 + lg*16);

    // prefetch steps 0..2
    f16x8 PB[4][2];
    PB[0][0] = *(const f16x8*)(bbase);
    PB[0][1] = *(const f16x8*)(bbase + 1024);
    PB[1][0] = *(const f16x8*)(bbase + 8192);
    PB[1][1] = *(const f16x8*)(bbase + 8192 + 1024);
    PB[2][0] = *(const f16x8*)(bbase + 2*8192);
    PB[2][1] = *(const f16x8*)(bbase + 2*8192 + 1024);

    __syncthreads();   // X ready; only barrier before the merge phase

    f32x4 acc[4][2];
    float rv1[4][4], rv2[4][4];
    int   ri1[4][4], ri2[4][4];
    #pragma unroll
    for (int m = 0; m < 4; ++m) {
        #pragma unroll
        for (int n = 0; n < 2; ++n) { f32x4 z = {0.f,0.f,0.f,0.f}; acc[m][n] = z; }
        #pragma unroll
        for (int j = 0; j < 4; ++j) {
            rv1[m][j] = 3.4e38f; rv2[m][j] = 3.4e38f;
            ri1[m][j] = 0x7fffffff; ri2[m][j] = 0x7fffffff;
        }
    }

    for (int ct = 0; ct < 32; ++ct) {
        #pragma unroll
        for (int su = 0; su < 4; ++su) {
            #pragma unroll
            for (int q = 0; q < 4; ++q) {
                const int s = ct*16 + su*4 + q;
                // prefetch step s+3 into static buffer (q+3)&3 (consumed at s-1)
                PB[(q+3)&3][0] = *(const f16x8*)(bbase + (size_t)(s+3)*8192);
                PB[(q+3)&3][1] = *(const f16x8*)(bbase + (size_t)(s+3)*8192 + 1024);
                const int dks = su*4 + q;   // compile-time per instance
                f16x8 A[4];
                #pragma unroll
                for (int m = 0; m < 4; ++m)
                    A[m] = *(const f16x8*)(&lds[(m*16 + l15)*1024
                                               + (((dks*4 + lg) ^ axor) * 16)]);
                #pragma unroll
                for (int m = 0; m < 4; ++m) {
                    acc[m][0] = __builtin_amdgcn_mfma_f32_16x16x32_f16(A[m], PB[q][0], acc[m][0], 0, 0, 0);
                    acc[m][1] = __builtin_amdgcn_mfma_f32_16x16x32_f16(A[m], PB[q][1], acc[m][1], 0, 0, 0);
                }
            }
        }
        // per-tile epilogue: score = ||c||^2 - 2*dot ; running top-2
        #pragma unroll
        for (int n = 0; n < 2; ++n) {
            const int col = (split*32 + ct)*128 + wid*32 + n*16 + l15;
            const float cn = cnorm[col];
            #pragma unroll
            for (int m = 0; m < 4; ++m) {
                #pragma unroll
                for (int j = 0; j < 4; ++j) {
                    const float sv = fmaf(-2.0f, acc[m][n][j], cn);
                    t2_update(sv, col, rv1[m][j], ri1[m][j], rv2[m][j], ri2[m][j]);
                }
                f32x4 z = {0.f,0.f,0.f,0.f};
                acc[m][n] = z;
            }
        }
    }

    // cross-lane top-2 merge over the 16 l15 lanes (same row, different cols)
    #pragma unroll
    for (int m = 0; m < 4; ++m)
        #pragma unroll
        for (int j = 0; j < 4; ++j) {
            #pragma unroll
            for (int off = 1; off <= 8; off <<= 1) {
                float b1 = __shfl_xor(rv1[m][j], off);
                float b2 = __shfl_xor(rv2[m][j], off);
                int  bi1 = __shfl_xor(ri1[m][j], off);
                int  bi2 = __shfl_xor(ri2[m][j], off);
                t2_merge(b1, bi1, b2, bi2, rv1[m][j], ri1[m][j], rv2[m][j], ri2[m][j]);
            }
        }

    // cross-wave merge over the 4 col-groups via LDS
    float* redv = (float*)&lds[0];      // [64][4][2]
    int*   redi = (int*)&lds[2048];     // [64][4][2]
    __syncthreads();                    // waves done reading X
    if (l15 == 0) {
        #pragma unroll
        for (int m = 0; m < 4; ++m)
            #pragma unroll
            for (int j = 0; j < 4; ++j) {
                const int rl = m*16 + lg*4 + j;
                redv[(rl*4 + wid)*2 + 0] = rv1[m][j];
                redv[(rl*4 + wid)*2 + 1] = rv2[m][j];
                redi[(rl*4 + wid)*2 + 0] = ri1[m][j];
                redi[(rl*4 + wid)*2 + 1] = ri2[m][j];
            }
    }
    __syncthreads();
    if (t < BM) {
        float a1 = redv[(t*4 + 0)*2 + 0], a2 = redv[(t*4 + 0)*2 + 1];
        int  ai1 = redi[(t*4 + 0)*2 + 0], ai2 = redi[(t*4 + 0)*2 + 1];
        #pragma unroll
        for (int w = 1; w < 4; ++w)
            t2_merge(redv[(t*4 + w)*2 + 0], redi[(t*4 + w)*2 + 0],
                     redv[(t*4 + w)*2 + 1], redi[(t*4 + w)*2 + 1],
                     a1, ai1, a2, ai2);
        const int row = rb + t;
        pmini4[row*4 + split*2 + 0] = ai1;
        pmini4[row*4 + split*2 + 1] = ai2;
    }
}

// ---- kernel 3: exact fp64 resolve of 4 candidates + write all outputs ----
__global__ __launch_bounds__(256) void vq_resolve4_out(
    const float* __restrict__ X, const float* __restrict__ CB,
    const int* __restrict__ pmini4, float* __restrict__ out)
{
    const int wid  = threadIdx.x >> 6;
    const int lane = threadIdx.x & 63;
    const int row  = blockIdx.x * 4 + wid;

    const float4* xp = (const float4*)(X + (size_t)row * DDIM + lane * 8);
    float4 xa = xp[0], xb = xp[1];

    double bd = 1.0e300;
    int    bi = 0x7fffffff;
    #pragma unroll
    for (int c = 0; c < 4; ++c) {
        const int idx = pmini4[row*4 + c];
        const float4* cp = (const float4*)(CB + (size_t)idx * DDIM + lane * 8);
        float4 ca = cp[0], cb2 = cp[1];
        double d = 0.0, e;
        e = (double)xa.x - ca.x;  d += e*e;  e = (double)xa.y - ca.y;  d += e*e;
        e = (double)xa.z - ca.z;  d += e*e;  e = (double)xa.w - ca.w;  d += e*e;
        e = (double)xb.x - cb2.x; d += e*e;  e = (double)xb.y - cb2.y; d += e*e;
        e = (double)xb.z - cb2.z; d += e*e;  e = (double)xb.w - cb2.w; d += e*e;
        #pragma unroll
        for (int off = 1; off < 64; off <<= 1) d += __shfl_xor(d, off);
        if (d < bd || (d == bd && idx < bi)) { bd = d; bi = idx; }
    }

    // gather winner row and write outputs
    const float4* wp = (const float4*)(CB + (size_t)bi * DDIM + lane * 8);
    float4 qa = wp[0], qb = wp[1];

    float4 qoa, loa, qob, lob;
    float d, s;
    d = qa.x - xa.x; qoa.x = xa.x + d; s = d*d; loa.x = s + 0.25f*s;
    d = qa.y - xa.y; qoa.y = xa.y + d; s = d*d; loa.y = s + 0.25f*s;
    d = qa.z - xa.z; qoa.z = xa.z + d; s = d*d; loa.z = s + 0.25f*s;
    d = qa.w - xa.w; qoa.w = xa.w + d; s = d*d; loa.w = s + 0.25f*s;
    d = qb.x - xb.x; qob.x = xb.x + d; s = d*d; lob.x = s + 0.25f*s;
    d = qb.y - xb.y; qob.y = xb.y + d; s = d*d; lob.y = s + 0.25f*s;
    d = qb.z - xb.z; qob.z = xb.z + d; s = d*d; lob.z = s + 0.25f*s;
    d = qb.w - xb.w; qob.w = xb.w + d; s = d*d; lob.w = s + 0.25f*s;

    ((float4*)out)[(size_t)row*128 + lane*2 + 0] = qoa;
    ((float4*)out)[(size_t)row*128 + lane*2 + 1] = qob;
    ((float4*)(out + O_LOSS))[(size_t)row*128 + lane*2 + 0] = loa;
    ((float4*)(out + O_LOSS))[(size_t)row*128 + lane*2 + 1] = lob;
    if (lane == 0) out[O_IDX + row] = (float)bi;
}

extern "C" void kernel_launch(void* const* d_in, const int* in_sizes, int n_in,
                              void* d_out, int out_size, void* d_ws, size_t ws_size,
                              hipStream_t stream)
{
    const float* X  = (const float*)d_in[0];
    const float* CB = (const float*)d_in[1];
    float* out = (float*)d_out;

    // big f16 scratch lives in out regions (fully rewritten afterwards)
    char* XsB  = (char*)out;              // 32 MB plain f16 X        (qout region)
    char* CBsB = (char*)(out + O_LOSS);   //  8 MB chunked f16 CB     (loss region)

    float* cnorm  = (float*)d_ws;             // 8192 floats
    int*   pmini4 = (int*)(cnorm + KCENT);    // 4*32768 ints

    vq_cvt_plain<<<(NROWS*64)/256, 256, 0, stream>>>(X, XsB);
    vq_cvt_cb<<<(KCENT*64)/256, 256, 0, stream>>>(CB, CBsB);
    vq_cnorm_kernel<<<KCENT/4, 256, 0, stream>>>(CB, cnorm, out + O_CNT);
    vq_topk_kernel<<<(NROWS/BM)*2, 256, 0, stream>>>(XsB, CBsB, cnorm, pmini4);
    vq_resolve4_out<<<NROWS/4, 256, 0, stream>>>(X, CB, pmini4, out);
    hipMemcpyAsync(out + O_CBV, CB, (size_t)KCENT * DDIM * sizeof(float),
                   hipMemcpyDeviceToDevice, stream);
}

// Round 7
// 1000.112 us; speedup vs baseline: 2.0129x; 2.0129x over previous
//
#include <hip/hip_runtime.h>

#define NROWS 32768
#define DDIM  512
#define KCENT 8192

// out layout (floats): qout[16777216] loss[16777216] idx[32768] cbv[4194304] counts[8192]
#define O_LOSS 16777216
#define O_IDX  33554432
#define O_CBV  33587200
#define O_CNT  37781504
#define O_PBLK 8388608      // float offset of pblk inside qout region (32 MB in)

typedef float f32x4 __attribute__((ext_vector_type(4)));
typedef _Float16 f16x8 __attribute__((ext_vector_type(8)));

// ---- kernel 0: fp32 -> f16, plain row-major ----
__global__ __launch_bounds__(256) void vq_cvt_plain(
    const float* __restrict__ src, char* __restrict__ dst)
{
    const size_t gid = (size_t)blockIdx.x * 256 + threadIdx.x;  // one 16B unit (8 f16)
    const float4* p = (const float4*)(src + gid * 8);
    float4 a = p[0], b = p[1];
    f16x8 h;
    h[0]=(_Float16)a.x; h[1]=(_Float16)a.y; h[2]=(_Float16)a.z; h[3]=(_Float16)a.w;
    h[4]=(_Float16)b.x; h[5]=(_Float16)b.y; h[6]=(_Float16)b.z; h[7]=(_Float16)b.w;
    *(f16x8*)(dst + gid * 16) = h;
}

// ---- kernel 1: centroid squared norms (fp64 accumulate) + counts=1 ----
__global__ __launch_bounds__(256) void vq_cnorm_kernel(
    const float* __restrict__ CB, float* __restrict__ cnorm, float* __restrict__ counts)
{
    const int wid  = threadIdx.x >> 6;
    const int lane = threadIdx.x & 63;
    const int cid  = blockIdx.x * 4 + wid;
    const float4* p = (const float4*)(CB + (size_t)cid * DDIM + lane * 8);
    float4 a = p[0], b = p[1];
    double s = (double)a.x*a.x + (double)a.y*a.y + (double)a.z*a.z + (double)a.w*a.w
             + (double)b.x*b.x + (double)b.y*b.y + (double)b.z*b.z + (double)b.w*b.w;
    #pragma unroll
    for (int off = 32; off > 0; off >>= 1) s += __shfl_down(s, off);
    if (lane == 0) { cnorm[cid] = (float)s; counts[cid] = 1.0f; }
}

__device__ __forceinline__ void t2_merge(float b1, int bi1, float b2, int bi2,
                                         float& a1, int& ai1, float& a2, int& ai2)
{
    if (b1 < a1 || (b1 == a1 && bi1 < ai1)) {
        float o1 = a1; int oi1 = ai1;
        a1 = b1; ai1 = bi1;
        if (b2 < o1 || (b2 == o1 && bi2 < oi1)) { a2 = b2; ai2 = bi2; }
        else                                    { a2 = o1; ai2 = oi1; }
    } else {
        if (b1 < a2 || (b1 == a2 && bi1 < ai2)) { a2 = b1; ai2 = bi1; }
    }
}

__device__ __forceinline__ void gl16(const char* g, const char* l)
{
    __builtin_amdgcn_global_load_lds(
        (const __attribute__((address_space(1))) void*)g,
        (__attribute__((address_space(3))) void*)l, 16, 0, 0);
}

// ---- kernel 2: m97-style 128x128 f16 GEMM tile + per-block per-row top-2 ----
// 512 thr, 8 waves (2 row-groups x 4 col-groups); A/B staged via global_load_lds;
// single-buffered, 2 barriers per K-step, 8 K-steps.
__global__ __launch_bounds__(512, 4) void vq_gemm_kernel(
    const char* __restrict__ Xf, const char* __restrict__ Cf,
    const float* __restrict__ cnorm, float4* __restrict__ pblk)
{
    __shared__ __align__(16) char lds[32768];   // A[128][64]f16 | B[128][64]f16

    // XCD mapping: xcd owns col-blocks [xcd*8, xcd*8+8) (1 MB CB slice, L2-resident)
    const int bid = blockIdx.x;
    const int xcd = bid & 7;
    const int idx = bid >> 3;            // 0..2047
    const int cb  = xcd * 8 + (idx & 7); // 0..63
    const int rb  = idx >> 3;            // 0..255

    const int t    = threadIdx.x;
    const int lane = t & 63;
    const int wid  = t >> 6;
    const int wr   = wid >> 2;    // 2 row-groups of 64
    const int wc   = wid & 3;     // 4 col-groups of 32
    const int l15  = lane & 15;
    const int lg   = lane >> 4;

    // staging: 1024 16B units per operand tile; thread covers units t and t+512
    const int r0 = t >> 3,        u0 = t & 7;
    const int r1 = (t + 512) >> 3, u1 = (t + 512) & 7;
    const size_t a0 = (size_t)(rb*128 + r0)*1024 + u0*16;
    const size_t a1 = (size_t)(rb*128 + r1)*1024 + u1*16;
    const size_t b0 = (size_t)(cb*128 + r0)*1024 + u0*16;
    const size_t b1 = (size_t)(cb*128 + r1)*1024 + u1*16;
    char* la0 = &lds[t*16];
    char* la1 = &lds[(t+512)*16];
    char* lb0 = &lds[16384 + t*16];
    char* lb1 = &lds[16384 + (t+512)*16];

    f32x4 z4 = {0.f, 0.f, 0.f, 0.f};
    f32x4 a00=z4, a01=z4, a10=z4, a11=z4, a20=z4, a21=z4, a30=z4, a31=z4;

    for (int dk = 0; dk < 8; ++dk) {
        __syncthreads();                       // prev compute done (no-op on dk=0)
        gl16(Xf + a0 + dk*128, la0);
        gl16(Xf + a1 + dk*128, la1);
        gl16(Cf + b0 + dk*128, lb0);
        gl16(Cf + b1 + dk*128, lb1);
        __syncthreads();                       // vmcnt(0) drain -> tiles visible

        #pragma unroll
        for (int ks = 0; ks < 2; ++ks) {
            const int ko = ks*64 + lg*16;
            f16x8 A0 = *(const f16x8*)(&lds[(wr*64 +  0 + l15)*128 + ko]);
            f16x8 A1 = *(const f16x8*)(&lds[(wr*64 + 16 + l15)*128 + ko]);
            f16x8 A2 = *(const f16x8*)(&lds[(wr*64 + 32 + l15)*128 + ko]);
            f16x8 A3 = *(const f16x8*)(&lds[(wr*64 + 48 + l15)*128 + ko]);
            f16x8 B0 = *(const f16x8*)(&lds[16384 + (wc*32 +  0 + l15)*128 + ko]);
            f16x8 B1 = *(const f16x8*)(&lds[16384 + (wc*32 + 16 + l15)*128 + ko]);
            a00 = __builtin_amdgcn_mfma_f32_16x16x32_f16(A0, B0, a00, 0, 0, 0);
            a01 = __builtin_amdgcn_mfma_f32_16x16x32_f16(A0, B1, a01, 0, 0, 0);
            a10 = __builtin_amdgcn_mfma_f32_16x16x32_f16(A1, B0, a10, 0, 0, 0);
            a11 = __builtin_amdgcn_mfma_f32_16x16x32_f16(A1, B1, a11, 0, 0, 0);
            a20 = __builtin_amdgcn_mfma_f32_16x16x32_f16(A2, B0, a20, 0, 0, 0);
            a21 = __builtin_amdgcn_mfma_f32_16x16x32_f16(A2, B1, a21, 0, 0, 0);
            a30 = __builtin_amdgcn_mfma_f32_16x16x32_f16(A3, B0, a30, 0, 0, 0);
            a31 = __builtin_amdgcn_mfma_f32_16x16x32_f16(A3, B1, a31, 0, 0, 0);
        }
    }
    __syncthreads();   // all compute done before LDS reuse for reduction

    // epilogue: per (m,j) row-slot, top-2 over this block's 128 cols
    const int colbase = cb*128 + wc*32;
    const float cn0 = cnorm[colbase + l15];
    const float cn1 = cnorm[colbase + 16 + l15];
    const int   c0  = colbase + l15;
    const int   c1  = colbase + 16 + l15;
    float4* redq = (float4*)&lds[0];    // [128 rows][4 wc]

    #define T2EPI(M, AC0, AC1)                                                   \
        _Pragma("unroll")                                                        \
        for (int j = 0; j < 4; ++j) {                                            \
            float s0 = fmaf(-2.0f, AC0[j], cn0);                                 \
            float s1 = fmaf(-2.0f, AC1[j], cn1);                                 \
            float v1, v2; int i1, i2;                                            \
            if (s0 <= s1) { v1=s0; i1=c0; v2=s1; i2=c1; }                        \
            else          { v1=s1; i1=c1; v2=s0; i2=c0; }                        \
            _Pragma("unroll")                                                    \
            for (int off = 1; off <= 8; off <<= 1) {                             \
                float e1 = __shfl_xor(v1, off), e2 = __shfl_xor(v2, off);        \
                int  f1 = __shfl_xor(i1, off),  f2 = __shfl_xor(i2, off);        \
                t2_merge(e1, f1, e2, f2, v1, i1, v2, i2);                        \
            }                                                                    \
            if (l15 == 0) {                                                      \
                float4 w; w.x = v1; w.y = __int_as_float(i1);                    \
                w.z = v2; w.w = __int_as_float(i2);                              \
                redq[(wr*64 + M*16 + lg*4 + j)*4 + wc] = w;                      \
            }                                                                    \
        }

    T2EPI(0, a00, a01)
    T2EPI(1, a10, a11)
    T2EPI(2, a20, a21)
    T2EPI(3, a30, a31)
    #undef T2EPI

    __syncthreads();
    if (t < 128) {
        float4 e0 = redq[t*4 + 0], e1 = redq[t*4 + 1];
        float4 e2 = redq[t*4 + 2], e3 = redq[t*4 + 3];
        float v1 = e0.x, v2 = e0.z;
        int   i1 = __float_as_int(e0.y), i2 = __float_as_int(e0.w);
        t2_merge(e1.x, __float_as_int(e1.y), e1.z, __float_as_int(e1.w), v1, i1, v2, i2);
        t2_merge(e2.x, __float_as_int(e2.y), e2.z, __float_as_int(e2.w), v1, i1, v2, i2);
        t2_merge(e3.x, __float_as_int(e3.y), e3.z, __float_as_int(e3.w), v1, i1, v2, i2);
        float4 w; w.x = v1; w.y = __int_as_float(i1); w.z = v2; w.w = __int_as_float(i2);
        pblk[((size_t)(rb*128 + t))*64 + cb] = w;
    }
}

// ---- kernel 3: merge 64 col-block top-2's per row -> global top-2 ----
__global__ __launch_bounds__(256) void vq_merge_kernel(
    const float4* __restrict__ pblk, int* __restrict__ pmini2)
{
    const int wid  = threadIdx.x >> 6;
    const int lane = threadIdx.x & 63;
    const int row  = blockIdx.x * 4 + wid;
    float4 e = pblk[(size_t)row*64 + lane];
    float v1 = e.x, v2 = e.z;
    int   i1 = __float_as_int(e.y), i2 = __float_as_int(e.w);
    #pragma unroll
    for (int off = 1; off < 64; off <<= 1) {
        float b1 = __shfl_xor(v1, off), b2 = __shfl_xor(v2, off);
        int  c1 = __shfl_xor(i1, off),  c2 = __shfl_xor(i2, off);
        t2_merge(b1, c1, b2, c2, v1, i1, v2, i2);
    }
    if (lane == 0) { pmini2[row*2 + 0] = i1; pmini2[row*2 + 1] = i2; }
}

// ---- kernel 4: exact fp64 resolve of the 2 candidates + write all outputs ----
__global__ __launch_bounds__(256) void vq_resolve_out(
    const float* __restrict__ X, const float* __restrict__ CB,
    const int* __restrict__ pmini2, float* __restrict__ out)
{
    const int wid  = threadIdx.x >> 6;
    const int lane = threadIdx.x & 63;
    const int row  = blockIdx.x * 4 + wid;
    const int i0 = pmini2[row*2 + 0], i1 = pmini2[row*2 + 1];

    const float4* xp = (const float4*)(X + (size_t)row * DDIM + lane * 8);
    float4 xa = xp[0], xb = xp[1];
    const float4* p0 = (const float4*)(CB + (size_t)i0 * DDIM + lane * 8);
    float4 c0a = p0[0], c0b = p0[1];
    const float4* p1 = (const float4*)(CB + (size_t)i1 * DDIM + lane * 8);
    float4 c1a = p1[0], c1b = p1[1];

    double d0 = 0.0, d1 = 0.0, e;
    e = (double)xa.x - c0a.x; d0 += e*e;  e = (double)xa.y - c0a.y; d0 += e*e;
    e = (double)xa.z - c0a.z; d0 += e*e;  e = (double)xa.w - c0a.w; d0 += e*e;
    e = (double)xb.x - c0b.x; d0 += e*e;  e = (double)xb.y - c0b.y; d0 += e*e;
    e = (double)xb.z - c0b.z; d0 += e*e;  e = (double)xb.w - c0b.w; d0 += e*e;
    e = (double)xa.x - c1a.x; d1 += e*e;  e = (double)xa.y - c1a.y; d1 += e*e;
    e = (double)xa.z - c1a.z; d1 += e*e;  e = (double)xa.w - c1a.w; d1 += e*e;
    e = (double)xb.x - c1b.x; d1 += e*e;  e = (double)xb.y - c1b.y; d1 += e*e;
    e = (double)xb.z - c1b.z; d1 += e*e;  e = (double)xb.w - c1b.w; d1 += e*e;
    #pragma unroll
    for (int off = 1; off < 64; off <<= 1) {
        d0 += __shfl_xor(d0, off);
        d1 += __shfl_xor(d1, off);
    }

    const bool w1 = (d1 < d0) || (d1 == d0 && i1 < i0);
    const int idxw = w1 ? i1 : i0;
    float4 qa, qb;
    qa.x = w1 ? c1a.x : c0a.x;  qa.y = w1 ? c1a.y : c0a.y;
    qa.z = w1 ? c1a.z : c0a.z;  qa.w = w1 ? c1a.w : c0a.w;
    qb.x = w1 ? c1b.x : c0b.x;  qb.y = w1 ? c1b.y : c0b.y;
    qb.z = w1 ? c1b.z : c0b.z;  qb.w = w1 ? c1b.w : c0b.w;

    float4 qoa, loa, qob, lob;
    float d, s;
    d = qa.x - xa.x; qoa.x = xa.x + d; s = d*d; loa.x = s + 0.25f*s;
    d = qa.y - xa.y; qoa.y = xa.y + d; s = d*d; loa.y = s + 0.25f*s;
    d = qa.z - xa.z; qoa.z = xa.z + d; s = d*d; loa.z = s + 0.25f*s;
    d = qa.w - xa.w; qoa.w = xa.w + d; s = d*d; loa.w = s + 0.25f*s;
    d = qb.x - xb.x; qob.x = xb.x + d; s = d*d; lob.x = s + 0.25f*s;
    d = qb.y - xb.y; qob.y = xb.y + d; s = d*d; lob.y = s + 0.25f*s;
    d = qb.z - xb.z; qob.z = xb.z + d; s = d*d; lob.z = s + 0.25f*s;
    d = qb.w - xb.w; qob.w = xb.w + d; s = d*d; lob.w = s + 0.25f*s;

    ((float4*)out)[(size_t)row*128 + lane*2 + 0] = qoa;
    ((float4*)out)[(size_t)row*128 + lane*2 + 1] = qob;
    ((float4*)(out + O_LOSS))[(size_t)row*128 + lane*2 + 0] = loa;
    ((float4*)(out + O_LOSS))[(size_t)row*128 + lane*2 + 1] = lob;
    if (lane == 0) out[O_IDX + row] = (float)idxw;
}

extern "C" void kernel_launch(void* const* d_in, const int* in_sizes, int n_in,
                              void* d_out, int out_size, void* d_ws, size_t ws_size,
                              hipStream_t stream)
{
    const float* X  = (const float*)d_in[0];
    const float* CB = (const float*)d_in[1];
    float* out = (float*)d_out;

    // big scratch parked in out regions (all rewritten by the final kernels)
    char*   XsB  = (char*)out;                    // 32 MB f16 X      (qout front half)
    float4* pblk = (float4*)(out + O_PBLK);       // 32 MB top-2/blk  (qout back half)
    char*   CBsB = (char*)(out + O_LOSS);         //  8 MB f16 CB     (loss region)

    float* cnorm  = (float*)d_ws;                 // 8192 floats
    int*   pmini2 = (int*)(cnorm + KCENT);        // 2*32768 ints

    vq_cvt_plain<<<(NROWS*64)/256, 256, 0, stream>>>(X, XsB);
    vq_cvt_plain<<<(KCENT*64)/256, 256, 0, stream>>>(CB, CBsB);
    vq_cnorm_kernel<<<KCENT/4, 256, 0, stream>>>(CB, cnorm, out + O_CNT);
    vq_gemm_kernel<<<(NROWS/128)*(KCENT/128), 512, 0, stream>>>(XsB, CBsB, cnorm, pblk);
    vq_merge_kernel<<<NROWS/4, 256, 0, stream>>>(pblk, pmini2);
    vq_resolve_out<<<NROWS/4, 256, 0, stream>>>(X, CB, pmini2, out);
    hipMemcpyAsync(out + O_CBV, CB, (size_t)KCENT * DDIM * sizeof(float),
                   hipMemcpyDeviceToDevice, stream);
}

// Round 8
// 790.982 us; speedup vs baseline: 2.5451x; 1.2644x over previous
//
#include <hip/hip_runtime.h>

#define NROWS 32768
#define DDIM  512
#define KCENT 8192

// out layout (floats): qout[16777216] loss[16777216] idx[32768] cbv[4194304] counts[8192]
#define O_LOSS 16777216
#define O_IDX  33554432
#define O_CBV  33587200
#define O_CNT  37781504
#define O_PBLK 8388608      // float offset of pblk inside qout region (32 MB in)

typedef float f32x4 __attribute__((ext_vector_type(4)));
typedef _Float16 f16x8 __attribute__((ext_vector_type(8)));

// ---- kernel 0: fp32 -> f16, 8-slot XOR pre-swizzle within each 128B K-chunk ----
// global unit g: row r = g>>6, w = g&63, chunk dk = w>>3, slot u = w&7.
// slot u of (r, dk) holds logical unit u^(r&7): source floats r*512 + (dk*8 + (u^(r&7)))*8
__global__ __launch_bounds__(256) void vq_cvt_swz8(
    const float* __restrict__ src, char* __restrict__ dst)
{
    const int gid = blockIdx.x * 256 + threadIdx.x;   // one 16B f16 unit (8 floats)
    const int r = gid >> 6, w = gid & 63, dk = w >> 3, u = w & 7;
    const float4* p = (const float4*)(src + (size_t)r * DDIM + (dk*8 + (u ^ (r & 7))) * 8);
    float4 a = p[0], b = p[1];
    f16x8 h;
    h[0]=(_Float16)a.x; h[1]=(_Float16)a.y; h[2]=(_Float16)a.z; h[3]=(_Float16)a.w;
    h[4]=(_Float16)b.x; h[5]=(_Float16)b.y; h[6]=(_Float16)b.z; h[7]=(_Float16)b.w;
    *(f16x8*)(dst + (size_t)gid * 16) = h;
}

// ---- kernel 1: centroid squared norms (fp64 accumulate) + counts=1 ----
__global__ __launch_bounds__(256) void vq_cnorm_kernel(
    const float* __restrict__ CB, float* __restrict__ cnorm, float* __restrict__ counts)
{
    const int wid  = threadIdx.x >> 6;
    const int lane = threadIdx.x & 63;
    const int cid  = blockIdx.x * 4 + wid;
    const float4* p = (const float4*)(CB + (size_t)cid * DDIM + lane * 8);
    float4 a = p[0], b = p[1];
    double s = (double)a.x*a.x + (double)a.y*a.y + (double)a.z*a.z + (double)a.w*a.w
             + (double)b.x*b.x + (double)b.y*b.y + (double)b.z*b.z + (double)b.w*b.w;
    #pragma unroll
    for (int off = 32; off > 0; off >>= 1) s += __shfl_down(s, off);
    if (lane == 0) { cnorm[cid] = (float)s; counts[cid] = 1.0f; }
}

__device__ __forceinline__ void t2_merge(float b1, int bi1, float b2, int bi2,
                                         float& a1, int& ai1, float& a2, int& ai2)
{
    if (b1 < a1 || (b1 == a1 && bi1 < ai1)) {
        float o1 = a1; int oi1 = ai1;
        a1 = b1; ai1 = bi1;
        if (b2 < o1 || (b2 == o1 && bi2 < oi1)) { a2 = b2; ai2 = bi2; }
        else                                    { a2 = o1; ai2 = oi1; }
    } else {
        if (b1 < a2 || (b1 == a2 && bi1 < ai2)) { a2 = b1; ai2 = bi1; }
    }
}

__device__ __forceinline__ void gl16(const char* g, const char* l)
{
    __builtin_amdgcn_global_load_lds(
        (const __attribute__((address_space(1))) void*)g,
        (__attribute__((address_space(3))) void*)l, 16, 0, 0);
}

// ---- kernel 2: m97-style 128x128 f16 GEMM tile + per-block per-row top-2 ----
// 512 thr, 8 waves (2 row-groups x 4 col-groups); A/B staged via global_load_lds
// (linear dest, global layout pre-swizzled); XOR on ds_read -> conflict-free.
__global__ __launch_bounds__(512, 4) void vq_gemm_kernel(
    const char* __restrict__ Xf, const char* __restrict__ Cf,
    const float* __restrict__ cnorm, float4* __restrict__ pblk)
{
    __shared__ __align__(16) char lds[32768];   // A[128][64]f16 | B[128][64]f16

    // XCD mapping: xcd owns col-blocks [xcd*8, xcd*8+8) (1 MB CB slice, L2-resident)
    const int bid = blockIdx.x;
    const int xcd = bid & 7;
    const int idx = bid >> 3;            // 0..2047
    const int cb  = xcd * 8 + (idx & 7); // 0..63
    const int rb  = idx >> 3;            // 0..255

    const int t    = threadIdx.x;
    const int lane = t & 63;
    const int wid  = t >> 6;
    const int wr   = wid >> 2;    // 2 row-groups of 64
    const int wc   = wid & 3;     // 4 col-groups of 32
    const int l15  = lane & 15;
    const int lg   = lane >> 4;

    // staging: 1024 16B units per operand tile; thread covers units t and t+512
    const int r0 = t >> 3,        u0 = t & 7;
    const int r1 = (t + 512) >> 3, u1 = (t + 512) & 7;
    const size_t a0 = (size_t)(rb*128 + r0)*1024 + u0*16;
    const size_t a1 = (size_t)(rb*128 + r1)*1024 + u1*16;
    const size_t b0 = (size_t)(cb*128 + r0)*1024 + u0*16;
    const size_t b1 = (size_t)(cb*128 + r1)*1024 + u1*16;
    char* la0 = &lds[t*16];
    char* la1 = &lds[(t+512)*16];
    char* lb0 = &lds[16384 + t*16];
    char* lb1 = &lds[16384 + (t+512)*16];

    f32x4 z4 = {0.f, 0.f, 0.f, 0.f};
    f32x4 a00=z4, a01=z4, a10=z4, a11=z4, a20=z4, a21=z4, a30=z4, a31=z4;

    for (int dk = 0; dk < 8; ++dk) {
        __syncthreads();                       // prev compute done (no-op on dk=0)
        gl16(Xf + a0 + dk*128, la0);
        gl16(Xf + a1 + dk*128, la1);
        gl16(Cf + b0 + dk*128, lb0);
        gl16(Cf + b1 + dk*128, lb1);
        __syncthreads();                       // vmcnt(0) drain -> tiles visible

        #pragma unroll
        for (int ks = 0; ks < 2; ++ks) {
            const int ku = ks*4 + lg;          // logical 16B unit within the K-chunk
            const int rA0 = wr*64 +  0 + l15, rA1 = wr*64 + 16 + l15;
            const int rA2 = wr*64 + 32 + l15, rA3 = wr*64 + 48 + l15;
            const int rB0 = wc*32 +  0 + l15, rB1 = wc*32 + 16 + l15;
            f16x8 A0 = *(const f16x8*)(&lds[rA0*128 + ((ku ^ (rA0 & 7)) * 16)]);
            f16x8 A1 = *(const f16x8*)(&lds[rA1*128 + ((ku ^ (rA1 & 7)) * 16)]);
            f16x8 A2 = *(const f16x8*)(&lds[rA2*128 + ((ku ^ (rA2 & 7)) * 16)]);
            f16x8 A3 = *(const f16x8*)(&lds[rA3*128 + ((ku ^ (rA3 & 7)) * 16)]);
            f16x8 B0 = *(const f16x8*)(&lds[16384 + rB0*128 + ((ku ^ (rB0 & 7)) * 16)]);
            f16x8 B1 = *(const f16x8*)(&lds[16384 + rB1*128 + ((ku ^ (rB1 & 7)) * 16)]);
            a00 = __builtin_amdgcn_mfma_f32_16x16x32_f16(A0, B0, a00, 0, 0, 0);
            a01 = __builtin_amdgcn_mfma_f32_16x16x32_f16(A0, B1, a01, 0, 0, 0);
            a10 = __builtin_amdgcn_mfma_f32_16x16x32_f16(A1, B0, a10, 0, 0, 0);
            a11 = __builtin_amdgcn_mfma_f32_16x16x32_f16(A1, B1, a11, 0, 0, 0);
            a20 = __builtin_amdgcn_mfma_f32_16x16x32_f16(A2, B0, a20, 0, 0, 0);
            a21 = __builtin_amdgcn_mfma_f32_16x16x32_f16(A2, B1, a21, 0, 0, 0);
            a30 = __builtin_amdgcn_mfma_f32_16x16x32_f16(A3, B0, a30, 0, 0, 0);
            a31 = __builtin_amdgcn_mfma_f32_16x16x32_f16(A3, B1, a31, 0, 0, 0);
        }
    }
    __syncthreads();   // all compute done before LDS reuse for reduction

    // epilogue: per (m,j) row-slot, top-2 over this block's 128 cols
    const int colbase = cb*128 + wc*32;
    const float cn0 = cnorm[colbase + l15];
    const float cn1 = cnorm[colbase + 16 + l15];
    const int   c0  = colbase + l15;
    const int   c1  = colbase + 16 + l15;
    float4* redq = (float4*)&lds[0];    // [128 rows][4 wc]

    #define T2EPI(M, AC0, AC1)                                                   \
        _Pragma("unroll")                                                        \
        for (int j = 0; j < 4; ++j) {                                            \
            float s0 = fmaf(-2.0f, AC0[j], cn0);                                 \
            float s1 = fmaf(-2.0f, AC1[j], cn1);                                 \
            float v1, v2; int i1, i2;                                            \
            if (s0 <= s1) { v1=s0; i1=c0; v2=s1; i2=c1; }                        \
            else          { v1=s1; i1=c1; v2=s0; i2=c0; }                        \
            _Pragma("unroll")                                                    \
            for (int off = 1; off <= 8; off <<= 1) {                             \
                float e1 = __shfl_xor(v1, off), e2 = __shfl_xor(v2, off);        \
                int  f1 = __shfl_xor(i1, off),  f2 = __shfl_xor(i2, off);        \
                t2_merge(e1, f1, e2, f2, v1, i1, v2, i2);                        \
            }                                                                    \
            if (l15 == 0) {                                                      \
                float4 w; w.x = v1; w.y = __int_as_float(i1);                    \
                w.z = v2; w.w = __int_as_float(i2);                              \
                redq[(wr*64 + M*16 + lg*4 + j)*4 + wc] = w;                      \
            }                                                                    \
        }

    T2EPI(0, a00, a01)
    T2EPI(1, a10, a11)
    T2EPI(2, a20, a21)
    T2EPI(3, a30, a31)
    #undef T2EPI

    __syncthreads();
    if (t < 128) {
        float4 e0 = redq[t*4 + 0], e1 = redq[t*4 + 1];
        float4 e2 = redq[t*4 + 2], e3 = redq[t*4 + 3];
        float v1 = e0.x, v2 = e0.z;
        int   i1 = __float_as_int(e0.y), i2 = __float_as_int(e0.w);
        t2_merge(e1.x, __float_as_int(e1.y), e1.z, __float_as_int(e1.w), v1, i1, v2, i2);
        t2_merge(e2.x, __float_as_int(e2.y), e2.z, __float_as_int(e2.w), v1, i1, v2, i2);
        t2_merge(e3.x, __float_as_int(e3.y), e3.z, __float_as_int(e3.w), v1, i1, v2, i2);
        float4 w; w.x = v1; w.y = __int_as_float(i1); w.z = v2; w.w = __int_as_float(i2);
        pblk[((size_t)(rb*128 + t))*64 + cb] = w;
    }
}

// ---- kernel 3: merge 64 col-block top-2's per row -> global top-2 ----
__global__ __launch_bounds__(256) void vq_merge_kernel(
    const float4* __restrict__ pblk, int* __restrict__ pmini2)
{
    const int wid  = threadIdx.x >> 6;
    const int lane = threadIdx.x & 63;
    const int row  = blockIdx.x * 4 + wid;
    float4 e = pblk[(size_t)row*64 + lane];
    float v1 = e.x, v2 = e.z;
    int   i1 = __float_as_int(e.y), i2 = __float_as_int(e.w);
    #pragma unroll
    for (int off = 1; off < 64; off <<= 1) {
        float b1 = __shfl_xor(v1, off), b2 = __shfl_xor(v2, off);
        int  c1 = __shfl_xor(i1, off),  c2 = __shfl_xor(i2, off);
        t2_merge(b1, c1, b2, c2, v1, i1, v2, i2);
    }
    if (lane == 0) { pmini2[row*2 + 0] = i1; pmini2[row*2 + 1] = i2; }
}

// ---- kernel 4: exact fp64 resolve of the 2 candidates + write all outputs ----
__global__ __launch_bounds__(256) void vq_resolve_out(
    const float* __restrict__ X, const float* __restrict__ CB,
    const int* __restrict__ pmini2, float* __restrict__ out)
{
    const int wid  = threadIdx.x >> 6;
    const int lane = threadIdx.x & 63;
    const int row  = blockIdx.x * 4 + wid;
    const int i0 = pmini2[row*2 + 0], i1 = pmini2[row*2 + 1];

    const float4* xp = (const float4*)(X + (size_t)row * DDIM + lane * 8);
    float4 xa = xp[0], xb = xp[1];
    const float4* p0 = (const float4*)(CB + (size_t)i0 * DDIM + lane * 8);
    float4 c0a = p0[0], c0b = p0[1];
    const float4* p1 = (const float4*)(CB + (size_t)i1 * DDIM + lane * 8);
    float4 c1a = p1[0], c1b = p1[1];

    double d0 = 0.0, d1 = 0.0, e;
    e = (double)xa.x - c0a.x; d0 += e*e;  e = (double)xa.y - c0a.y; d0 += e*e;
    e = (double)xa.z - c0a.z; d0 += e*e;  e = (double)xa.w - c0a.w; d0 += e*e;
    e = (double)xb.x - c0b.x; d0 += e*e;  e = (double)xb.y - c0b.y; d0 += e*e;
    e = (double)xb.z - c0b.z; d0 += e*e;  e = (double)xb.w - c0b.w; d0 += e*e;
    e = (double)xa.x - c1a.x; d1 += e*e;  e = (double)xa.y - c1a.y; d1 += e*e;
    e = (double)xa.z - c1a.z; d1 += e*e;  e = (double)xa.w - c1a.w; d1 += e*e;
    e = (double)xb.x - c1b.x; d1 += e*e;  e = (double)xb.y - c1b.y; d1 += e*e;
    e = (double)xb.z - c1b.z; d1 += e*e;  e = (double)xb.w - c1b.w; d1 += e*e;
    #pragma unroll
    for (int off = 1; off < 64; off <<= 1) {
        d0 += __shfl_xor(d0, off);
        d1 += __shfl_xor(d1, off);
    }

    const bool w1 = (d1 < d0) || (d1 == d0 && i1 < i0);
    const int idxw = w1 ? i1 : i0;
    float4 qa, qb;
    qa.x = w1 ? c1a.x : c0a.x;  qa.y = w1 ? c1a.y : c0a.y;
    qa.z = w1 ? c1a.z : c0a.z;  qa.w = w1 ? c1a.w : c0a.w;
    qb.x = w1 ? c1b.x : c0b.x;  qb.y = w1 ? c1b.y : c0b.y;
    qb.z = w1 ? c1b.z : c0b.z;  qb.w = w1 ? c1b.w : c0b.w;

    float4 qoa, loa, qob, lob;
    float d, s;
    d = qa.x - xa.x; qoa.x = xa.x + d; s = d*d; loa.x = s + 0.25f*s;
    d = qa.y - xa.y; qoa.y = xa.y + d; s = d*d; loa.y = s + 0.25f*s;
    d = qa.z - xa.z; qoa.z = xa.z + d; s = d*d; loa.z = s + 0.25f*s;
    d = qa.w - xa.w; qoa.w = xa.w + d; s = d*d; loa.w = s + 0.25f*s;
    d = qb.x - xb.x; qob.x = xb.x + d; s = d*d; lob.x = s + 0.25f*s;
    d = qb.y - xb.y; qob.y = xb.y + d; s = d*d; lob.y = s + 0.25f*s;
    d = qb.z - xb.z; qob.z = xb.z + d; s = d*d; lob.z = s + 0.25f*s;
    d = qb.w - xb.w; qob.w = xb.w + d; s = d*d; lob.w = s + 0.25f*s;

    ((float4*)out)[(size_t)row*128 + lane*2 + 0] = qoa;
    ((float4*)out)[(size_t)row*128 + lane*2 + 1] = qob;
    ((float4*)(out + O_LOSS))[(size_t)row*128 + lane*2 + 0] = loa;
    ((float4*)(out + O_LOSS))[(size_t)row*128 + lane*2 + 1] = lob;
    if (lane == 0) out[O_IDX + row] = (float)idxw;
}

extern "C" void kernel_launch(void* const* d_in, const int* in_sizes, int n_in,
                              void* d_out, int out_size, void* d_ws, size_t ws_size,
                              hipStream_t stream)
{
    const float* X  = (const float*)d_in[0];
    const float* CB = (const float*)d_in[1];
    float* out = (float*)d_out;

    // big scratch parked in out regions (all rewritten by the final kernels)
    char*   XsB  = (char*)out;                    // 32 MB f16 X      (qout front half)
    float4* pblk = (float4*)(out + O_PBLK);       // 32 MB top-2/blk  (qout back half)
    char*   CBsB = (char*)(out + O_LOSS);         //  8 MB f16 CB     (loss region)

    float* cnorm  = (float*)d_ws;                 // 8192 floats
    int*   pmini2 = (int*)(cnorm + KCENT);        // 2*32768 ints

    vq_cvt_swz8<<<(NROWS*64)/256, 256, 0, stream>>>(X, XsB);
    vq_cvt_swz8<<<(KCENT*64)/256, 256, 0, stream>>>(CB, CBsB);
    vq_cnorm_kernel<<<KCENT/4, 256, 0, stream>>>(CB, cnorm, out + O_CNT);
    vq_gemm_kernel<<<(NROWS/128)*(KCENT/128), 512, 0, stream>>>(XsB, CBsB, cnorm, pblk);
    vq_merge_kernel<<<NROWS/4, 256, 0, stream>>>(pblk, pmini2);
    vq_resolve_out<<<NROWS/4, 256, 0, stream>>>(X, CB, pmini2, out);
    hipMemcpyAsync(out + O_CBV, CB, (size_t)KCENT * DDIM * sizeof(float),
                   hipMemcpyDeviceToDevice, stream);
}

// Round 9
// 762.759 us; speedup vs baseline: 2.6393x; 1.0370x over previous
//
#include <hip/hip_runtime.h>

#define NROWS 32768
#define DDIM  512
#define KCENT 8192

// out layout (floats): qout[16777216] loss[16777216] idx[32768] cbv[4194304] counts[8192]
#define O_LOSS 16777216
#define O_IDX  33554432
#define O_CBV  33587200
#define O_CNT  37781504
#define O_PBLK 8388608      // float offset of pblk inside qout region (32 MB in)

typedef float f32x4 __attribute__((ext_vector_type(4)));
typedef _Float16 f16x8 __attribute__((ext_vector_type(8)));

// ---- kernel 0: fp32 -> f16, 8-slot XOR pre-swizzle within each 128B K-chunk ----
// global unit g: row r = g>>6, w = g&63, chunk dk = w>>3, slot u = w&7.
// slot u of (r, dk) holds logical unit u^(r&7): source floats r*512 + (dk*8 + (u^(r&7)))*8
__global__ __launch_bounds__(256) void vq_cvt_swz8(
    const float* __restrict__ src, char* __restrict__ dst)
{
    const int gid = blockIdx.x * 256 + threadIdx.x;   // one 16B f16 unit (8 floats)
    const int r = gid >> 6, w = gid & 63, dk = w >> 3, u = w & 7;
    const float4* p = (const float4*)(src + (size_t)r * DDIM + (dk*8 + (u ^ (r & 7))) * 8);
    float4 a = p[0], b = p[1];
    f16x8 h;
    h[0]=(_Float16)a.x; h[1]=(_Float16)a.y; h[2]=(_Float16)a.z; h[3]=(_Float16)a.w;
    h[4]=(_Float16)b.x; h[5]=(_Float16)b.y; h[6]=(_Float16)b.z; h[7]=(_Float16)b.w;
    *(f16x8*)(dst + (size_t)gid * 16) = h;
}

// ---- kernel 1: centroid squared norms (fp64 accumulate) + counts=1 ----
__global__ __launch_bounds__(256) void vq_cnorm_kernel(
    const float* __restrict__ CB, float* __restrict__ cnorm, float* __restrict__ counts)
{
    const int wid  = threadIdx.x >> 6;
    const int lane = threadIdx.x & 63;
    const int cid  = blockIdx.x * 4 + wid;
    const float4* p = (const float4*)(CB + (size_t)cid * DDIM + lane * 8);
    float4 a = p[0], b = p[1];
    double s = (double)a.x*a.x + (double)a.y*a.y + (double)a.z*a.z + (double)a.w*a.w
             + (double)b.x*b.x + (double)b.y*b.y + (double)b.z*b.z + (double)b.w*b.w;
    #pragma unroll
    for (int off = 32; off > 0; off >>= 1) s += __shfl_down(s, off);
    if (lane == 0) { cnorm[cid] = (float)s; counts[cid] = 1.0f; }
}

__device__ __forceinline__ void t2_merge(float b1, int bi1, float b2, int bi2,
                                         float& a1, int& ai1, float& a2, int& ai2)
{
    if (b1 < a1 || (b1 == a1 && bi1 < ai1)) {
        float o1 = a1; int oi1 = ai1;
        a1 = b1; ai1 = bi1;
        if (b2 < o1 || (b2 == o1 && bi2 < oi1)) { a2 = b2; ai2 = bi2; }
        else                                    { a2 = o1; ai2 = oi1; }
    } else {
        if (b1 < a2 || (b1 == a2 && bi1 < ai2)) { a2 = b1; ai2 = bi1; }
    }
}

__device__ __forceinline__ void gl16(const char* g, const char* l)
{
    __builtin_amdgcn_global_load_lds(
        (const __attribute__((address_space(1))) void*)g,
        (__attribute__((address_space(3))) void*)l, 16, 0, 0);
}

// ---- kernel 2: m97-style 128x128 f16 GEMM tile + per-block per-row top-2 ----
// 512 thr, 8 waves (2 row-groups x 4 col-groups); A/B staged via global_load_lds
// (linear dest, global layout pre-swizzled); XOR on ds_read -> conflict-free.
// __launch_bounds__(512, 8): 8 waves/EU = 32 waves/CU = 4 blocks/CU (LDS 4x32KB=128KB).
__global__ __launch_bounds__(512, 8) void vq_gemm_kernel(
    const char* __restrict__ Xf, const char* __restrict__ Cf,
    const float* __restrict__ cnorm, float4* __restrict__ pblk)
{
    __shared__ __align__(16) char lds[32768];   // A[128][64]f16 | B[128][64]f16

    // XCD mapping: xcd owns col-blocks [xcd*8, xcd*8+8) (1 MB CB slice, L2-resident)
    const int bid = blockIdx.x;
    const int xcd = bid & 7;
    const int idx = bid >> 3;            // 0..2047
    const int cb  = xcd * 8 + (idx & 7); // 0..63
    const int rb  = idx >> 3;            // 0..255

    const int t    = threadIdx.x;
    const int lane = t & 63;
    const int wid  = t >> 6;
    const int wr   = wid >> 2;    // 2 row-groups of 64
    const int wc   = wid & 3;     // 4 col-groups of 32
    const int l15  = lane & 15;
    const int lg   = lane >> 4;

    // staging: 1024 16B units per operand tile; thread covers units t and t+512
    const int r0 = t >> 3,        u0 = t & 7;
    const int r1 = (t + 512) >> 3, u1 = (t + 512) & 7;
    const size_t a0 = (size_t)(rb*128 + r0)*1024 + u0*16;
    const size_t a1 = (size_t)(rb*128 + r1)*1024 + u1*16;
    const size_t b0 = (size_t)(cb*128 + r0)*1024 + u0*16;
    const size_t b1 = (size_t)(cb*128 + r1)*1024 + u1*16;
    char* la0 = &lds[t*16];
    char* la1 = &lds[(t+512)*16];
    char* lb0 = &lds[16384 + t*16];
    char* lb1 = &lds[16384 + (t+512)*16];

    f32x4 z4 = {0.f, 0.f, 0.f, 0.f};
    f32x4 a00=z4, a01=z4, a10=z4, a11=z4, a20=z4, a21=z4, a30=z4, a31=z4;

    for (int dk = 0; dk < 8; ++dk) {
        __syncthreads();                       // prev compute done (no-op on dk=0)
        gl16(Xf + a0 + dk*128, la0);
        gl16(Xf + a1 + dk*128, la1);
        gl16(Cf + b0 + dk*128, lb0);
        gl16(Cf + b1 + dk*128, lb1);
        __syncthreads();                       // vmcnt(0) drain -> tiles visible

        #pragma unroll
        for (int ks = 0; ks < 2; ++ks) {
            const int ku = ks*4 + lg;          // logical 16B unit within the K-chunk
            const int rA0 = wr*64 +  0 + l15, rA1 = wr*64 + 16 + l15;
            const int rA2 = wr*64 + 32 + l15, rA3 = wr*64 + 48 + l15;
            const int rB0 = wc*32 +  0 + l15, rB1 = wc*32 + 16 + l15;
            f16x8 A0 = *(const f16x8*)(&lds[rA0*128 + ((ku ^ (rA0 & 7)) * 16)]);
            f16x8 A1 = *(const f16x8*)(&lds[rA1*128 + ((ku ^ (rA1 & 7)) * 16)]);
            f16x8 A2 = *(const f16x8*)(&lds[rA2*128 + ((ku ^ (rA2 & 7)) * 16)]);
            f16x8 A3 = *(const f16x8*)(&lds[rA3*128 + ((ku ^ (rA3 & 7)) * 16)]);
            f16x8 B0 = *(const f16x8*)(&lds[16384 + rB0*128 + ((ku ^ (rB0 & 7)) * 16)]);
            f16x8 B1 = *(const f16x8*)(&lds[16384 + rB1*128 + ((ku ^ (rB1 & 7)) * 16)]);
            a00 = __builtin_amdgcn_mfma_f32_16x16x32_f16(A0, B0, a00, 0, 0, 0);
            a01 = __builtin_amdgcn_mfma_f32_16x16x32_f16(A0, B1, a01, 0, 0, 0);
            a10 = __builtin_amdgcn_mfma_f32_16x16x32_f16(A1, B0, a10, 0, 0, 0);
            a11 = __builtin_amdgcn_mfma_f32_16x16x32_f16(A1, B1, a11, 0, 0, 0);
            a20 = __builtin_amdgcn_mfma_f32_16x16x32_f16(A2, B0, a20, 0, 0, 0);
            a21 = __builtin_amdgcn_mfma_f32_16x16x32_f16(A2, B1, a21, 0, 0, 0);
            a30 = __builtin_amdgcn_mfma_f32_16x16x32_f16(A3, B0, a30, 0, 0, 0);
            a31 = __builtin_amdgcn_mfma_f32_16x16x32_f16(A3, B1, a31, 0, 0, 0);
        }
    }
    __syncthreads();   // all compute done before LDS reuse for reduction

    // epilogue: per (m,j) row-slot, top-2 over this block's 128 cols
    const int colbase = cb*128 + wc*32;
    const float cn0 = cnorm[colbase + l15];
    const float cn1 = cnorm[colbase + 16 + l15];
    const int   c0  = colbase + l15;
    const int   c1  = colbase + 16 + l15;
    float4* redq = (float4*)&lds[0];    // [128 rows][4 wc]

    #define T2EPI(M, AC0, AC1)                                                   \
        _Pragma("unroll")                                                        \
        for (int j = 0; j < 4; ++j) {                                            \
            float s0 = fmaf(-2.0f, AC0[j], cn0);                                 \
            float s1 = fmaf(-2.0f, AC1[j], cn1);                                 \
            float v1, v2; int i1, i2;                                            \
            if (s0 <= s1) { v1=s0; i1=c0; v2=s1; i2=c1; }                        \
            else          { v1=s1; i1=c1; v2=s0; i2=c0; }                        \
            _Pragma("unroll")                                                    \
            for (int off = 1; off <= 8; off <<= 1) {                             \
                float e1 = __shfl_xor(v1, off), e2 = __shfl_xor(v2, off);        \
                int  f1 = __shfl_xor(i1, off),  f2 = __shfl_xor(i2, off);        \
                t2_merge(e1, f1, e2, f2, v1, i1, v2, i2);                        \
            }                                                                    \
            if (l15 == 0) {                                                      \
                float4 w; w.x = v1; w.y = __int_as_float(i1);                    \
                w.z = v2; w.w = __int_as_float(i2);                              \
                redq[(wr*64 + M*16 + lg*4 + j)*4 + wc] = w;                      \
            }                                                                    \
        }

    T2EPI(0, a00, a01)
    T2EPI(1, a10, a11)
    T2EPI(2, a20, a21)
    T2EPI(3, a30, a31)
    #undef T2EPI

    __syncthreads();
    if (t < 128) {
        float4 e0 = redq[t*4 + 0], e1 = redq[t*4 + 1];
        float4 e2 = redq[t*4 + 2], e3 = redq[t*4 + 3];
        float v1 = e0.x, v2 = e0.z;
        int   i1 = __float_as_int(e0.y), i2 = __float_as_int(e0.w);
        t2_merge(e1.x, __float_as_int(e1.y), e1.z, __float_as_int(e1.w), v1, i1, v2, i2);
        t2_merge(e2.x, __float_as_int(e2.y), e2.z, __float_as_int(e2.w), v1, i1, v2, i2);
        t2_merge(e3.x, __float_as_int(e3.y), e3.z, __float_as_int(e3.w), v1, i1, v2, i2);
        float4 w; w.x = v1; w.y = __int_as_float(i1); w.z = v2; w.w = __int_as_float(i2);
        pblk[((size_t)(rb*128 + t))*64 + cb] = w;
    }
}

// ---- kernel 3: merge 64 col-block top-2's per row -> global top-2 ----
__global__ __launch_bounds__(256) void vq_merge_kernel(
    const float4* __restrict__ pblk, int* __restrict__ pmini2)
{
    const int wid  = threadIdx.x >> 6;
    const int lane = threadIdx.x & 63;
    const int row  = blockIdx.x * 4 + wid;
    float4 e = pblk[(size_t)row*64 + lane];
    float v1 = e.x, v2 = e.z;
    int   i1 = __float_as_int(e.y), i2 = __float_as_int(e.w);
    #pragma unroll
    for (int off = 1; off < 64; off <<= 1) {
        float b1 = __shfl_xor(v1, off), b2 = __shfl_xor(v2, off);
        int  c1 = __shfl_xor(i1, off),  c2 = __shfl_xor(i2, off);
        t2_merge(b1, c1, b2, c2, v1, i1, v2, i2);
    }
    if (lane == 0) { pmini2[row*2 + 0] = i1; pmini2[row*2 + 1] = i2; }
}

// ---- kernel 4: exact fp64 resolve of the 2 candidates + write all outputs ----
__global__ __launch_bounds__(256) void vq_resolve_out(
    const float* __restrict__ X, const float* __restrict__ CB,
    const int* __restrict__ pmini2, float* __restrict__ out)
{
    const int wid  = threadIdx.x >> 6;
    const int lane = threadIdx.x & 63;
    const int row  = blockIdx.x * 4 + wid;
    const int i0 = pmini2[row*2 + 0], i1 = pmini2[row*2 + 1];

    const float4* xp = (const float4*)(X + (size_t)row * DDIM + lane * 8);
    float4 xa = xp[0], xb = xp[1];
    const float4* p0 = (const float4*)(CB + (size_t)i0 * DDIM + lane * 8);
    float4 c0a = p0[0], c0b = p0[1];
    const float4* p1 = (const float4*)(CB + (size_t)i1 * DDIM + lane * 8);
    float4 c1a = p1[0], c1b = p1[1];

    double d0 = 0.0, d1 = 0.0, e;
    e = (double)xa.x - c0a.x; d0 += e*e;  e = (double)xa.y - c0a.y; d0 += e*e;
    e = (double)xa.z - c0a.z; d0 += e*e;  e = (double)xa.w - c0a.w; d0 += e*e;
    e = (double)xb.x - c0b.x; d0 += e*e;  e = (double)xb.y - c0b.y; d0 += e*e;
    e = (double)xb.z - c0b.z; d0 += e*e;  e = (double)xb.w - c0b.w; d0 += e*e;
    e = (double)xa.x - c1a.x; d1 += e*e;  e = (double)xa.y - c1a.y; d1 += e*e;
    e = (double)xa.z - c1a.z; d1 += e*e;  e = (double)xa.w - c1a.w; d1 += e*e;
    e = (double)xb.x - c1b.x; d1 += e*e;  e = (double)xb.y - c1b.y; d1 += e*e;
    e = (double)xb.z - c1b.z; d1 += e*e;  e = (double)xb.w - c1b.w; d1 += e*e;
    #pragma unroll
    for (int off = 1; off < 64; off <<= 1) {
        d0 += __shfl_xor(d0, off);
        d1 += __shfl_xor(d1, off);
    }

    const bool w1 = (d1 < d0) || (d1 == d0 && i1 < i0);
    const int idxw = w1 ? i1 : i0;
    float4 qa, qb;
    qa.x = w1 ? c1a.x : c0a.x;  qa.y = w1 ? c1a.y : c0a.y;
    qa.z = w1 ? c1a.z : c0a.z;  qa.w = w1 ? c1a.w : c0a.w;
    qb.x = w1 ? c1b.x : c0b.x;  qb.y = w1 ? c1b.y : c0b.y;
    qb.z = w1 ? c1b.z : c0b.z;  qb.w = w1 ? c1b.w : c0b.w;

    float4 qoa, loa, qob, lob;
    float d, s;
    d = qa.x - xa.x; qoa.x = xa.x + d; s = d*d; loa.x = s + 0.25f*s;
    d = qa.y - xa.y; qoa.y = xa.y + d; s = d*d; loa.y = s + 0.25f*s;
    d = qa.z - xa.z; qoa.z = xa.z + d; s = d*d; loa.z = s + 0.25f*s;
    d = qa.w - xa.w; qoa.w = xa.w + d; s = d*d; loa.w = s + 0.25f*s;
    d = qb.x - xb.x; qob.x = xb.x + d; s = d*d; lob.x = s + 0.25f*s;
    d = qb.y - xb.y; qob.y = xb.y + d; s = d*d; lob.y = s + 0.25f*s;
    d = qb.z - xb.z; qob.z = xb.z + d; s = d*d; lob.z = s + 0.25f*s;
    d = qb.w - xb.w; qob.w = xb.w + d; s = d*d; lob.w = s + 0.25f*s;

    ((float4*)out)[(size_t)row*128 + lane*2 + 0] = qoa;
    ((float4*)out)[(size_t)row*128 + lane*2 + 1] = qob;
    ((float4*)(out + O_LOSS))[(size_t)row*128 + lane*2 + 0] = loa;
    ((float4*)(out + O_LOSS))[(size_t)row*128 + lane*2 + 1] = lob;
    if (lane == 0) out[O_IDX + row] = (float)idxw;
}

extern "C" void kernel_launch(void* const* d_in, const int* in_sizes, int n_in,
                              void* d_out, int out_size, void* d_ws, size_t ws_size,
                              hipStream_t stream)
{
    const float* X  = (const float*)d_in[0];
    const float* CB = (const float*)d_in[1];
    float* out = (float*)d_out;

    // big scratch parked in out regions (all rewritten by the final kernels)
    char*   XsB  = (char*)out;                    // 32 MB f16 X      (qout front half)
    float4* pblk = (float4*)(out + O_PBLK);       // 32 MB top-2/blk  (qout back half)
    char*   CBsB = (char*)(out + O_LOSS);         //  8 MB f16 CB     (loss region)

    float* cnorm  = (float*)d_ws;                 // 8192 floats
    int*   pmini2 = (int*)(cnorm + KCENT);        // 2*32768 ints

    vq_cvt_swz8<<<(NROWS*64)/256, 256, 0, stream>>>(X, XsB);
    vq_cvt_swz8<<<(KCENT*64)/256, 256, 0, stream>>>(CB, CBsB);
    vq_cnorm_kernel<<<KCENT/4, 256, 0, stream>>>(CB, cnorm, out + O_CNT);
    vq_gemm_kernel<<<(NROWS/128)*(KCENT/128), 512, 0, stream>>>(XsB, CBsB, cnorm, pblk);
    vq_merge_kernel<<<NROWS/4, 256, 0, stream>>>(pblk, pmini2);
    vq_resolve_out<<<NROWS/4, 256, 0, stream>>>(X, CB, pmini2, out);
    hipMemcpyAsync(out + O_CBV, CB, (size_t)KCENT * DDIM * sizeof(float),
                   hipMemcpyDeviceToDevice, stream);
}